// Round 2
// baseline (8562.274 us; speedup 1.0000x reference)
//
#include <hip/hip_runtime.h>

#define B_SZ   256
#define D_IN   512
#define T_LEN  512
#define H_DIM  1024
#define KTOT   1536   // H_DIM + D_IN
#define NCLASS 1000

using half8    = __attribute__((ext_vector_type(8))) _Float16;
using floatx4  = __attribute__((ext_vector_type(4))) float;
using floatx16 = __attribute__((ext_vector_type(16))) float;

__device__ __forceinline__ float ftanh(float x) {
    x = fminf(fmaxf(x, -20.f), 20.f);
    float e = __expf(2.f * x);
    return (e - 1.f) / (e + 1.f);
}

// ---------------------------------------------------------------------------
// Transpose x [B][D][T] fp32 -> xT [T][B][D] f16 (so step-kernel A-loads are
// contiguous in the contraction dim).
// ---------------------------------------------------------------------------
__global__ void k_transpose_x(const float* __restrict__ x, _Float16* __restrict__ xT) {
    __shared__ float tile[32][33];
    int b = blockIdx.z, d0 = blockIdx.y * 32, t0 = blockIdx.x * 32;
    int tx = threadIdx.x, ty = threadIdx.y;   // 32 x 8
    const float* xp = x + ((size_t)b * D_IN + d0) * T_LEN + t0;
#pragma unroll
    for (int i = 0; i < 4; ++i)
        tile[ty + i * 8][tx] = xp[(size_t)(ty + i * 8) * T_LEN + tx];
    __syncthreads();
#pragma unroll
    for (int i = 0; i < 4; ++i) {
        int t = t0 + ty + i * 8;
        xT[((size_t)t * B_SZ + b) * D_IN + d0 + tx] = (_Float16)tile[tx][ty + i * 8];
    }
}

// ---------------------------------------------------------------------------
// Build WcatT [4096][1536] f16, column-major weights: WcatT[n][k].
// n = gate*1024 + j, gate order g,f,i,o.  k<1024 -> Wh[k][j], k>=1024 -> Wx[k-1024][j].
// ---------------------------------------------------------------------------
__global__ void k_build_wcat(const float* __restrict__ Wgh, const float* __restrict__ Wfh,
                             const float* __restrict__ Wih, const float* __restrict__ Woh,
                             const float* __restrict__ Wgx, const float* __restrict__ Wfx,
                             const float* __restrict__ Wix, const float* __restrict__ Wox,
                             _Float16* __restrict__ WcatT) {
    int src = blockIdx.z;                 // 0..3 = Wh g,f,i,o ; 4..7 = Wx g,f,i,o
    int kmax = (src < 4) ? 1024 : 512;
    int koff = (src < 4) ? 0 : 1024;
    int gi = src & 3;
    const float* W;
    switch (src) {
        case 0: W = Wgh; break; case 1: W = Wfh; break;
        case 2: W = Wih; break; case 3: W = Woh; break;
        case 4: W = Wgx; break; case 5: W = Wfx; break;
        case 6: W = Wix; break; default: W = Wox; break;
    }
    int k0 = blockIdx.y * 32;
    if (k0 >= kmax) return;
    int j0 = blockIdx.x * 32;
    __shared__ float tile[32][33];
    int tx = threadIdx.x, ty = threadIdx.y;   // 32 x 8
#pragma unroll
    for (int i = 0; i < 4; ++i)
        tile[ty + i * 8][tx] = W[(size_t)(k0 + ty + i * 8) * 1024 + j0 + tx];
    __syncthreads();
#pragma unroll
    for (int i = 0; i < 4; ++i) {
        int n = gi * 1024 + j0 + ty + i * 8;
        WcatT[(size_t)n * KTOT + koff + k0 + tx] = (_Float16)tile[tx][ty + i * 8];
    }
}

// ---------------------------------------------------------------------------
// Init: zero c, zero h buffer 0, build concatenated bias [4096] (g,f,i,o).
// ---------------------------------------------------------------------------
__global__ void k_init(float* __restrict__ c, unsigned int* __restrict__ h0u,
                       float* __restrict__ bias,
                       const float* __restrict__ bg, const float* __restrict__ bf,
                       const float* __restrict__ bi, const float* __restrict__ bo) {
    int idx = blockIdx.x * 256 + threadIdx.x;          // grid 1024 -> 262144
    if (idx < 262144) c[idx] = 0.f;
    if (idx < 131072) h0u[idx] = 0u;                   // 262144 halves
    if (idx < 4096) {
        int gi = idx >> 10, j = idx & 1023;
        float v = (gi == 0) ? bg[j] : (gi == 1) ? bf[j] : (gi == 2) ? bi[j] : bo[j];
        bias[idx] = v;
    }
}

// ---------------------------------------------------------------------------
// Raw barrier: lgkmcnt(0) gives cross-wave LDS-write visibility; raw s_barrier
// does NOT drain vmcnt -> in-flight global prefetch (A stage + B frags) survives.
// ---------------------------------------------------------------------------
__device__ __forceinline__ void bar() {
    asm volatile("s_waitcnt lgkmcnt(0)" ::: "memory");
    __builtin_amdgcn_s_barrier();
    asm volatile("" ::: "memory");
}

// ---------------------------------------------------------------------------
// One recurrence step. Grid 256 x 256 threads (4 waves), 1 block/CU.
// Block owns 64 batch rows x 16 h-cols (all 4 gates). 32x32x16 MFMA:
// wave = (row-group rg2 of 32 rows) x (gate-pair gp).  A (h|x) staged in LDS
// (double-buffered); B (weights) loaded per-lane direct from L2-resident WcatT
// with a 4-deep register rotation.  One raw barrier per K-chunk of 64.
// Epilogue: cross-wave gate exchange through eps[], then c/h update.
// ---------------------------------------------------------------------------
__global__ __launch_bounds__(256)
void k_step(const _Float16* __restrict__ h_in, _Float16* __restrict__ h_out,
            float* __restrict__ h_f32, float* __restrict__ c_st,
            const _Float16* __restrict__ xTt, const _Float16* __restrict__ WcatT,
            const float* __restrict__ bias, int is_last) {
    __shared__ __align__(16) _Float16 As[2][64][72];   // 64 rows x 64 k (+8 pad)
    __shared__ float eps[64][65];                      // gate exchange, padded

    int bid = blockIdx.x;
    int xcd = bid & 7, idx = bid >> 3;
    int cg = xcd * 8 + (idx & 7);     // [0,64) h-col group -> same-XCD L2 locality
    int rg = idx >> 3;                // [0,4)  batch group (64 rows)
    int r0 = rg * 64, hc0 = cg * 16;

    int tid = threadIdx.x, wave = tid >> 6, lane = tid & 63;
    int rg2 = wave >> 1, gp = wave & 1;

    floatx16 acc;
#pragma unroll
    for (int i = 0; i < 16; ++i) acc[i] = 0.f;

    // A staging decomposition: 64 rows x 64 halves, 256 threads x 32 B
    int arow = tid >> 2, ac16 = (tid & 3) << 4;
    const _Float16* hbase = h_in + (size_t)(r0 + arow) * H_DIM + ac16;
    const _Float16* xbase = xTt + (size_t)(r0 + arow) * D_IN + ac16;

    // B direct per-lane fragment pointer: n-col j in [0,32) = 2 gates x 16 hcols
    int j = lane & 31;
    int nrow = (gp * 2 + (j >> 4)) * 1024 + hc0 + (j & 15);
    const _Float16* bptr = WcatT + (size_t)nrow * KTOT + ((lane >> 5) << 3);

    // A fragment coordinates
    int ard = rg2 * 32 + (lane & 31);
    int akb = (lane >> 5) << 3;

#define LOADA(A0, A1, c) do {                                                   \
        const _Float16* _sa = ((c) < 16) ? (hbase + ((c) << 6))                 \
                                         : (xbase + (((c) - 16) << 6));         \
        A0 = ((const uint4*)_sa)[0]; A1 = ((const uint4*)_sa)[1];               \
    } while (0)

#define STOREA(A0, A1, buf) do {                                                \
        *(uint4*)&As[buf][arow][ac16]     = A0;                                 \
        *(uint4*)&As[buf][arow][ac16 + 8] = A1;                                 \
    } while (0)

#define LOADB(S, c) do {                                                        \
        S[0] = *(const half8*)(bptr + ((c) << 6));                              \
        S[1] = *(const half8*)(bptr + ((c) << 6) + 16);                         \
        S[2] = *(const half8*)(bptr + ((c) << 6) + 32);                         \
        S[3] = *(const half8*)(bptr + ((c) << 6) + 48);                         \
    } while (0)

#define MFMA_CHUNK(buf, S) do {                                                 \
        _Pragma("unroll")                                                       \
        for (int ks = 0; ks < 4; ++ks) {                                        \
            half8 af = *(const half8*)&As[buf][ard][ks * 16 + akb];             \
            acc = __builtin_amdgcn_mfma_f32_32x32x16_f16(af, S[ks], acc, 0, 0, 0); \
        }                                                                       \
    } while (0)

    uint4 aE0, aE1, aO0, aO1;         // A prefetch (even / odd chunk streams)
    half8 Bst[4][4];                  // B fragment rotation, chunk c -> Bst[c&3]

    // prologue
    LOADA(aE0, aE1, 0);
    LOADA(aO0, aO1, 1);
    LOADB(Bst[0], 0); LOADB(Bst[1], 1); LOADB(Bst[2], 2); LOADB(Bst[3], 3);
    STOREA(aE0, aE1, 0);
    LOADA(aE0, aE1, 2);
    bar();

#pragma unroll
    for (int cc = 0; cc < 12; ++cc) {
        const int e = 2 * cc, o = e + 1;
        // invariant: buf0 = chunk e (ready); aO holds chunk o; aE = chunk e+2 in flight
        STOREA(aO0, aO1, 1);                       // stage chunk o -> buf1
        MFMA_CHUNK(0, Bst[e & 3]);                 // compute chunk e
        if (e + 4 < 24) LOADB(Bst[e & 3], e + 4);
        if (o + 2 < 24) LOADA(aO0, aO1, o + 2);
        bar();
        if (e + 2 < 24) STOREA(aE0, aE1, 0);       // stage chunk e+2 -> buf0
        MFMA_CHUNK(1, Bst[o & 3]);                 // compute chunk o
        if (o + 4 < 24) LOADB(Bst[o & 3], o + 4);
        if (e + 4 < 24) LOADA(aE0, aE1, e + 4);
        bar();
    }

#undef LOADA
#undef STOREA
#undef LOADB
#undef MFMA_CHUNK

    // ---- epilogue: exchange gate activations across waves --------------------
    // C/D layout (32x32): col = lane&31, row = (reg&3) + 8*(reg>>2) + 4*(lane>>5)
#pragma unroll
    for (int r = 0; r < 16; ++r) {
        int row_m = ((lane >> 5) << 2) + (r & 3) + ((r >> 2) << 3);
        eps[rg2 * 32 + row_m][(gp << 5) + j] = acc[r];
    }
    __syncthreads();

    int hcol = tid & 15;
    int rbase = (tid >> 4) << 2;
    float bg_ = bias[hc0 + hcol],        bf_ = bias[1024 + hc0 + hcol];
    float bi_ = bias[2048 + hc0 + hcol], bo_ = bias[3072 + hc0 + hcol];
#pragma unroll
    for (int rr = 0; rr < 4; ++rr) {
        int row = rbase + rr;
        size_t off = (size_t)(r0 + row) * H_DIM + hc0 + hcol;
        float g  = ftanh(eps[row][hcol]      + bg_);
        float f  = ftanh(eps[row][16 + hcol] + bf_);
        float ii = ftanh(eps[row][32 + hcol] + bi_);
        float o  = ftanh(eps[row][48 + hcol] + bo_);
        float cn = g * ii + c_st[off] * f;
        c_st[off] = cn;
        float hn = ftanh(cn) * o;
        h_out[off] = (_Float16)hn;
        if (is_last) h_f32[off] = hn;
    }
}

// ---------------------------------------------------------------------------
// logits[256][1024(pad)] = h @ W_ph + b_p   (fp32 vector; tiny GEMM)
// ---------------------------------------------------------------------------
__global__ void k_logits(const float* __restrict__ h, const float* __restrict__ Wp,
                         const float* __restrict__ bp, float* __restrict__ logits) {
    __shared__ float hs[32][65];
    int r0 = blockIdx.y * 32;
    int c0 = blockIdx.x * 64;
    int tid = threadIdx.x;
    int wave = tid >> 6, tx = tid & 63;
    int col = c0 + tx;
    float s[8];
#pragma unroll
    for (int i = 0; i < 8; ++i) s[i] = 0.f;
    for (int kc = 0; kc < 16; ++kc) {
        int k0 = kc * 64;
#pragma unroll
        for (int i = 0; i < 8; ++i) {
            int idx = tid + i * 256;
            hs[idx >> 6][idx & 63] = h[(size_t)(r0 + (idx >> 6)) * H_DIM + k0 + (idx & 63)];
        }
        __syncthreads();
        if (col < NCLASS) {
            for (int kk = 0; kk < 64; ++kk) {
                float wv = Wp[(size_t)(k0 + kk) * NCLASS + col];
#pragma unroll
                for (int rr = 0; rr < 8; ++rr) s[rr] += hs[wave * 8 + rr][kk] * wv;
            }
        }
        __syncthreads();
    }
    if (col < NCLASS) {
#pragma unroll
        for (int rr = 0; rr < 8; ++rr)
            logits[(size_t)(r0 + wave * 8 + rr) * 1024 + col] = s[rr] + bp[col];
    }
}

// ---------------------------------------------------------------------------
// Row softmax over 1000 classes -> d_out [256][1000] fp32
// ---------------------------------------------------------------------------
__global__ void k_softmax(const float* __restrict__ logits, float* __restrict__ out) {
    __shared__ float red[256];
    int row = blockIdx.x, tid = threadIdx.x;
    float v[4];
    float mx = -1e30f;
#pragma unroll
    for (int i = 0; i < 4; ++i) {
        int c = tid + i * 256;
        float z = (c < NCLASS) ? logits[(size_t)row * 1024 + c] : -1e30f;
        v[i] = z;
        mx = fmaxf(mx, z);
    }
    red[tid] = mx; __syncthreads();
    for (int s = 128; s > 0; s >>= 1) {
        if (tid < s) red[tid] = fmaxf(red[tid], red[tid + s]);
        __syncthreads();
    }
    mx = red[0]; __syncthreads();
    float sum = 0.f;
#pragma unroll
    for (int i = 0; i < 4; ++i) {
        int c = tid + i * 256;
        v[i] = (c < NCLASS) ? __expf(v[i] - mx) : 0.f;
        sum += v[i];
    }
    red[tid] = sum; __syncthreads();
    for (int s = 128; s > 0; s >>= 1) {
        if (tid < s) red[tid] += red[tid + s];
        __syncthreads();
    }
    float inv = 1.f / red[0];
#pragma unroll
    for (int i = 0; i < 4; ++i) {
        int c = tid + i * 256;
        if (c < NCLASS) out[(size_t)row * NCLASS + c] = v[i] * inv;
    }
}

// ---------------------------------------------------------------------------
extern "C" void kernel_launch(void* const* d_in, const int* in_sizes, int n_in,
                              void* d_out, int out_size, void* d_ws, size_t ws_size,
                              hipStream_t stream) {
    const float* x   = (const float*)d_in[0];
    const float* Wfx = (const float*)d_in[1];
    const float* Wfh = (const float*)d_in[2];
    const float* Wgx = (const float*)d_in[3];
    const float* Wgh = (const float*)d_in[4];
    const float* Wix = (const float*)d_in[5];
    const float* Wih = (const float*)d_in[6];
    const float* Wox = (const float*)d_in[7];
    const float* Woh = (const float*)d_in[8];
    const float* Wph = (const float*)d_in[9];
    const float* bf  = (const float*)d_in[10];
    const float* bg  = (const float*)d_in[11];
    const float* bi  = (const float*)d_in[12];
    const float* bo  = (const float*)d_in[13];
    const float* bp  = (const float*)d_in[14];
    float* outp = (float*)d_out;

    char* ws = (char*)d_ws;
    _Float16* xT    = (_Float16*)(ws);                       // 134217728
    _Float16* WcatT = (_Float16*)(ws + 134217728);           // 12582912
    float*    bias  = (float*)   (ws + 146800640);           // 16384
    _Float16* hb0   = (_Float16*)(ws + 146817024);           // 524288
    _Float16* hb1   = (_Float16*)(ws + 147341312);           // 524288
    float*    c_st  = (float*)   (ws + 147865600);           // 1048576
    float*    hf32  = (float*)   (ws + 148914176);           // 1048576
    float*    logit = (float*)   (ws + 149962752);           // 1048576

    k_transpose_x<<<dim3(16, 16, 256), dim3(32, 8), 0, stream>>>(x, xT);
    k_build_wcat<<<dim3(32, 32, 8), dim3(32, 8), 0, stream>>>(
        Wgh, Wfh, Wih, Woh, Wgx, Wfx, Wix, Wox, WcatT);
    k_init<<<1024, 256, 0, stream>>>(c_st, (unsigned int*)hb0, bias, bg, bf, bi, bo);

    for (int t = 0; t < T_LEN; ++t) {
        const _Float16* hin = (t & 1) ? hb1 : hb0;
        _Float16*       hout = (t & 1) ? hb0 : hb1;
        k_step<<<256, 256, 0, stream>>>(hin, hout, hf32, c_st,
                                        xT + (size_t)t * B_SZ * D_IN, WcatT, bias,
                                        (t == T_LEN - 1) ? 1 : 0);
    }

    k_logits<<<dim3(16, 8), 256, 0, stream>>>(hf32, Wph, bp, logit);
    k_softmax<<<256, 256, 0, stream>>>(logit, outp);
}

// Round 3
// 6983.038 us; speedup vs baseline: 1.2262x; 1.2262x over previous
//
#include <hip/hip_runtime.h>

#define B_SZ   256
#define D_IN   512
#define T_LEN  512
#define H_DIM  1024
#define KTOT   1536   // H_DIM + D_IN
#define NCLASS 1000

using half8    = __attribute__((ext_vector_type(8))) _Float16;
using floatx4  = __attribute__((ext_vector_type(4))) float;
using floatx16 = __attribute__((ext_vector_type(16))) float;

__device__ __forceinline__ float ftanh(float x) {
    x = fminf(fmaxf(x, -20.f), 20.f);
    float e = __expf(2.f * x);
    return (e - 1.f) / (e + 1.f);
}

// ---------------------------------------------------------------------------
// Transpose x [B][D][T] fp32 -> xT [T][B][D] f16 (contraction-contiguous).
// ---------------------------------------------------------------------------
__global__ void k_transpose_x(const float* __restrict__ x, _Float16* __restrict__ xT) {
    __shared__ float tile[32][33];
    int b = blockIdx.z, d0 = blockIdx.y * 32, t0 = blockIdx.x * 32;
    int tx = threadIdx.x, ty = threadIdx.y;   // 32 x 8
    const float* xp = x + ((size_t)b * D_IN + d0) * T_LEN + t0;
#pragma unroll
    for (int i = 0; i < 4; ++i)
        tile[ty + i * 8][tx] = xp[(size_t)(ty + i * 8) * T_LEN + tx];
    __syncthreads();
#pragma unroll
    for (int i = 0; i < 4; ++i) {
        int t = t0 + ty + i * 8;
        xT[((size_t)t * B_SZ + b) * D_IN + d0 + tx] = (_Float16)tile[tx][ty + i * 8];
    }
}

// ---------------------------------------------------------------------------
// Build Wswz: B-fragment-swizzled weights.
// Cell (cg, c, ks, cq, lane) is 16B holding 8 f16:
//   n  = (2*cq + ((lane&31)>>4))*1024 + cg*16 + ((lane&31)&15)   [gate order g,f,i,o]
//   k  = c*64 + ks*16 + (lane>>5)*8 + e
// Linear: Wswz[ (((cg*24 + c)*4 + ks)*2 + cq)*64*8 + lane*8 + e ]
// ---------------------------------------------------------------------------
__global__ void k_build_wswz(const float* __restrict__ Wgh, const float* __restrict__ Wfh,
                             const float* __restrict__ Wih, const float* __restrict__ Woh,
                             const float* __restrict__ Wgx, const float* __restrict__ Wfx,
                             const float* __restrict__ Wix, const float* __restrict__ Wox,
                             _Float16* __restrict__ Wswz) {
    int c  = blockIdx.x;      // 0..23  (k-chunk of 64)
    int cg = blockIdx.y;      // 0..63  (16 h-cols)
    int hc0 = cg * 16;
    __shared__ float tile[4][64][17];   // [gate][k-local][hcol]
    int kbase = c * 64;
    int isx = kbase >= 1024;
    int kb = isx ? (kbase - 1024) : kbase;
    int t = threadIdx.x;
    int h15 = t & 15, kl = t >> 4;      // kl 0..15
    const float* Wh0 = Wgh; const float* Wh1 = Wfh; const float* Wh2 = Wih; const float* Wh3 = Woh;
    const float* Wx0 = Wgx; const float* Wx1 = Wfx; const float* Wx2 = Wix; const float* Wx3 = Wox;
#pragma unroll
    for (int g = 0; g < 4; ++g) {
        const float* W = isx ? (g == 0 ? Wx0 : g == 1 ? Wx1 : g == 2 ? Wx2 : Wx3)
                             : (g == 0 ? Wh0 : g == 1 ? Wh1 : g == 2 ? Wh2 : Wh3);
#pragma unroll
        for (int s = 0; s < 4; ++s)
            tile[g][kl + 16 * s][h15] = W[(size_t)(kb + kl + 16 * s) * 1024 + hc0 + h15];
    }
    __syncthreads();
    int ks = t >> 6, l = t & 63;
    int j = l & 31, gh = j >> 4, jh = j & 15, kh = (l >> 5) * 8;
#pragma unroll
    for (int cq = 0; cq < 2; ++cq) {
        int g = 2 * cq + gh;
        half8 v;
#pragma unroll
        for (int e = 0; e < 8; ++e)
            v[e] = (_Float16)tile[g][ks * 16 + kh + e][jh];
        size_t cell = (((size_t)(cg * 24 + c) * 4 + ks) * 2 + cq);
        *(half8*)(Wswz + cell * 512 + (size_t)l * 8) = v;
    }
}

// ---------------------------------------------------------------------------
// Init: zero c, zero swizzled-h buffer 0, build concatenated bias (g,f,i,o).
// ---------------------------------------------------------------------------
__global__ void k_init(float* __restrict__ c, unsigned int* __restrict__ h0u,
                       float* __restrict__ bias,
                       const float* __restrict__ bg, const float* __restrict__ bf,
                       const float* __restrict__ bi, const float* __restrict__ bo) {
    int idx = blockIdx.x * 256 + threadIdx.x;          // grid 1024 -> 262144
    if (idx < 262144) c[idx] = 0.f;
    if (idx < 131072) h0u[idx] = 0u;                   // 262144 halves
    if (idx < 4096) {
        int gi = idx >> 10, j = idx & 1023;
        float v = (gi == 0) ? bg[j] : (gi == 1) ? bf[j] : (gi == 2) ? bi[j] : bo[j];
        bias[idx] = v;
    }
}

// ---------------------------------------------------------------------------
// One recurrence step. Grid 256 x 256 threads (4 waves), 1 block/CU.
// Block owns 64 batch rows (rg) x 16 h-cols (cg), all 4 gates (64 n-cols).
// K-SPLIT across waves: wave w handles chunks {w, w+4, ..., w+20} (6 of 24).
// Main loop has ZERO LDS and ZERO barriers: A-h and B fragments loaded
// coalesced from pre-swizzled global (hA / Wswz); A-x scattered from xT.
// Register double-buffer, 2-chunk lookahead.
// Epilogue: banded cross-wave k-reduction via LDS xch, gate math, h written
// back in A-fragment-swizzled layout for the next step.
//
// hA layout: cell (rg, c[0..15], ks, rq, lane) 16B:
//   row(block-local) = rq*32 + (lane&31), k = c*64+ks*16+(lane>>5)*8+e
//   offset f16 = rg*65536 + ((c*4+ks)*2+rq)*512 + lane*8
// ---------------------------------------------------------------------------
__global__ __launch_bounds__(256)
void k_step(const _Float16* __restrict__ hA_in, _Float16* __restrict__ hA_out,
            float* __restrict__ h_f32, float* __restrict__ c_st,
            const _Float16* __restrict__ xTt, const _Float16* __restrict__ Wswz,
            const float* __restrict__ bias, int is_last) {
    __shared__ __align__(16) float xch[16][64][20];     // [band*4+srcwave][col][row(4-pad)]
    __shared__ __align__(16) _Float16 hswz[64][16];     // h tile for swizzled write-back

    int bid = blockIdx.x;
    int xcd = bid & 7, idx = bid >> 3;
    int cg = xcd * 8 + (idx & 7);     // [0,64) h-col group -> same-XCD L2 locality
    int rg = idx >> 3;                // [0,4)  batch group (64 rows)
    int r0 = rg * 64, hc0 = cg * 16;

    int tid = threadIdx.x, w = tid >> 6, lane = tid & 63;
    int l31 = lane & 31, lh = lane >> 5;

    floatx16 acc[2][2];
#pragma unroll
    for (int a = 0; a < 2; ++a)
#pragma unroll
        for (int b = 0; b < 2; ++b)
#pragma unroll
            for (int i = 0; i < 16; ++i) acc[a][b][i] = 0.f;

    // per-lane fragment base pointers (pre-offset by wave's chunk base c0 = w)
    const _Float16* pAh = hA_in + (size_t)rg * 65536 + (size_t)w * 4096 + (size_t)lane * 8;
    const _Float16* pB  = Wswz  + (size_t)cg * 98304 + (size_t)w * 4096 + (size_t)lane * 8;
    const _Float16* pAx = xTt + (size_t)(r0 + l31) * D_IN + (size_t)w * 64 + lh * 8;

    // early prefetch of c-state (consumed in epilogue)
    int hcol = lane & 15;
    int rb4  = (lane >> 4) * 4;
    float cold[4];
#pragma unroll
    for (int rr = 0; rr < 4; ++rr)
        cold[rr] = c_st[(size_t)(r0 + 16 * w + rb4 + rr) * H_DIM + hc0 + hcol];

    half8 Af[2][2][4];   // [set][rq][ks]
    half8 Bf[2][2][4];   // [set][cq][ks]

#define LOADC_H(S, I) do {                                                        \
        _Pragma("unroll") for (int ks = 0; ks < 4; ++ks) {                        \
            _Pragma("unroll") for (int q = 0; q < 2; ++q) {                       \
                Af[S][q][ks] = *(const half8*)(pAh + (I) * 16384 + ks * 1024 + q * 512); \
                Bf[S][q][ks] = *(const half8*)(pB  + (I) * 16384 + ks * 1024 + q * 512); \
            } } } while (0)

#define LOADC_X(S, I) do {                                                        \
        _Pragma("unroll") for (int ks = 0; ks < 4; ++ks) {                        \
            _Pragma("unroll") for (int q = 0; q < 2; ++q) {                       \
                Af[S][q][ks] = *(const half8*)(pAx + q * (32 * D_IN) + ((I) - 4) * 256 + ks * 16); \
                Bf[S][q][ks] = *(const half8*)(pB  + (I) * 16384 + ks * 1024 + q * 512); \
            } } } while (0)

#define MFMAC(S) do {                                                             \
        _Pragma("unroll") for (int ks = 0; ks < 4; ++ks)                          \
            _Pragma("unroll") for (int rq = 0; rq < 2; ++rq)                      \
                _Pragma("unroll") for (int cq = 0; cq < 2; ++cq)                  \
                    acc[rq][cq] = __builtin_amdgcn_mfma_f32_32x32x16_f16(         \
                        Af[S][rq][ks], Bf[S][cq][ks], acc[rq][cq], 0, 0, 0);      \
    } while (0)

    LOADC_H(0, 0);
    LOADC_H(1, 1);
#pragma unroll
    for (int i = 0; i < 6; ++i) {
        const int S = i & 1;
        MFMAC(S);
        const int ip = i + 2;
        if (ip < 4)      { LOADC_H(S, ip); }
        else if (ip < 6) { LOADC_X(S, ip); }
    }

#undef LOADC_H
#undef LOADC_X
#undef MFMAC

    // ---- banded cross-wave k-reduction ----------------------------------
    // C/D layout (verified R2): col = cq*32+(lane&31),
    //   row(block-local) = rq*32 + 4*(lane>>5) + (r&3) + 8*(r>>2)
    // band(row) = row>>4; wave w owns band w (rows 16w..16w+16).
#pragma unroll
    for (int rq = 0; rq < 2; ++rq)
#pragma unroll
        for (int cq = 0; cq < 2; ++cq)
#pragma unroll
            for (int rb = 0; rb < 4; ++rb) {
                int band = rq * 2 + (rb >> 1);
                int row0 = 4 * lh + 8 * (rb & 1);
                int col  = cq * 32 + l31;
                floatx4 v = { acc[rq][cq][rb * 4 + 0], acc[rq][cq][rb * 4 + 1],
                              acc[rq][cq][rb * 4 + 2], acc[rq][cq][rb * 4 + 3] };
                *(floatx4*)&xch[band * 4 + w][col][row0] = v;
            }
    __syncthreads();

    // owner wave w: sum 4 k-slices for its band, rows rb4..rb4+4, col gate*16+hcol
    floatx4 sums[4];
#pragma unroll
    for (int g2 = 0; g2 < 4; ++g2) {
        floatx4 s = { 0.f, 0.f, 0.f, 0.f };
#pragma unroll
        for (int s4 = 0; s4 < 4; ++s4)
            s += *(const floatx4*)&xch[w * 4 + s4][g2 * 16 + hcol][rb4];
        sums[g2] = s;
    }

    float bg_ = bias[hc0 + hcol],        bf_ = bias[1024 + hc0 + hcol];
    float bi_ = bias[2048 + hc0 + hcol], bo_ = bias[3072 + hc0 + hcol];
#pragma unroll
    for (int rr = 0; rr < 4; ++rr) {
        int growl = 16 * w + rb4 + rr;          // block-local row
        size_t off = (size_t)(r0 + growl) * H_DIM + hc0 + hcol;
        float g  = ftanh(sums[0][rr] + bg_);
        float f  = ftanh(sums[1][rr] + bf_);
        float ii = ftanh(sums[2][rr] + bi_);
        float o  = ftanh(sums[3][rr] + bo_);
        float cn = g * ii + cold[rr] * f;
        c_st[off] = cn;
        float hn = ftanh(cn) * o;
        hswz[growl][hcol] = (_Float16)hn;
        if (is_last) h_f32[off] = hn;
    }
    __syncthreads();

    // write h back in A-fragment-swizzled layout: 2 cells (rq=0,1)
    if (tid < 128) {
        int rq = tid >> 6, l = tid & 63;
        half8 v = *(const half8*)&hswz[rq * 32 + (l & 31)][(l >> 5) * 8];
        *(half8*)(hA_out + (size_t)rg * 65536 + ((size_t)cg * 2 + rq) * 512 + (size_t)l * 8) = v;
    }
}

// ---------------------------------------------------------------------------
// logits[256][1024(pad)] = h @ W_ph + b_p   (fp32 vector; tiny GEMM)
// ---------------------------------------------------------------------------
__global__ void k_logits(const float* __restrict__ h, const float* __restrict__ Wp,
                         const float* __restrict__ bp, float* __restrict__ logits) {
    __shared__ float hs[32][65];
    int r0 = blockIdx.y * 32;
    int c0 = blockIdx.x * 64;
    int tid = threadIdx.x;
    int wave = tid >> 6, tx = tid & 63;
    int col = c0 + tx;
    float s[8];
#pragma unroll
    for (int i = 0; i < 8; ++i) s[i] = 0.f;
    for (int kc = 0; kc < 16; ++kc) {
        int k0 = kc * 64;
#pragma unroll
        for (int i = 0; i < 8; ++i) {
            int idx = tid + i * 256;
            hs[idx >> 6][idx & 63] = h[(size_t)(r0 + (idx >> 6)) * H_DIM + k0 + (idx & 63)];
        }
        __syncthreads();
        if (col < NCLASS) {
            for (int kk = 0; kk < 64; ++kk) {
                float wv = Wp[(size_t)(k0 + kk) * NCLASS + col];
#pragma unroll
                for (int rr = 0; rr < 8; ++rr) s[rr] += hs[wave * 8 + rr][kk] * wv;
            }
        }
        __syncthreads();
    }
    if (col < NCLASS) {
#pragma unroll
        for (int rr = 0; rr < 8; ++rr)
            logits[(size_t)(r0 + wave * 8 + rr) * 1024 + col] = s[rr] + bp[col];
    }
}

// ---------------------------------------------------------------------------
// Row softmax over 1000 classes -> d_out [256][1000] fp32
// ---------------------------------------------------------------------------
__global__ void k_softmax(const float* __restrict__ logits, float* __restrict__ out) {
    __shared__ float red[256];
    int row = blockIdx.x, tid = threadIdx.x;
    float v[4];
    float mx = -1e30f;
#pragma unroll
    for (int i = 0; i < 4; ++i) {
        int c = tid + i * 256;
        float z = (c < NCLASS) ? logits[(size_t)row * 1024 + c] : -1e30f;
        v[i] = z;
        mx = fmaxf(mx, z);
    }
    red[tid] = mx; __syncthreads();
    for (int s = 128; s > 0; s >>= 1) {
        if (tid < s) red[tid] = fmaxf(red[tid], red[tid + s]);
        __syncthreads();
    }
    mx = red[0]; __syncthreads();
    float sum = 0.f;
#pragma unroll
    for (int i = 0; i < 4; ++i) {
        int c = tid + i * 256;
        v[i] = (c < NCLASS) ? __expf(v[i] - mx) : 0.f;
        sum += v[i];
    }
    red[tid] = sum; __syncthreads();
    for (int s = 128; s > 0; s >>= 1) {
        if (tid < s) red[tid] += red[tid + s];
        __syncthreads();
    }
    float inv = 1.f / red[0];
#pragma unroll
    for (int i = 0; i < 4; ++i) {
        int c = tid + i * 256;
        if (c < NCLASS) out[(size_t)row * NCLASS + c] = v[i] * inv;
    }
}

// ---------------------------------------------------------------------------
extern "C" void kernel_launch(void* const* d_in, const int* in_sizes, int n_in,
                              void* d_out, int out_size, void* d_ws, size_t ws_size,
                              hipStream_t stream) {
    const float* x   = (const float*)d_in[0];
    const float* Wfx = (const float*)d_in[1];
    const float* Wfh = (const float*)d_in[2];
    const float* Wgx = (const float*)d_in[3];
    const float* Wgh = (const float*)d_in[4];
    const float* Wix = (const float*)d_in[5];
    const float* Wih = (const float*)d_in[6];
    const float* Wox = (const float*)d_in[7];
    const float* Woh = (const float*)d_in[8];
    const float* Wph = (const float*)d_in[9];
    const float* bf  = (const float*)d_in[10];
    const float* bg  = (const float*)d_in[11];
    const float* bi  = (const float*)d_in[12];
    const float* bo  = (const float*)d_in[13];
    const float* bp  = (const float*)d_in[14];
    float* outp = (float*)d_out;

    char* ws = (char*)d_ws;
    _Float16* xT    = (_Float16*)(ws);                       // 134217728
    _Float16* Wswz  = (_Float16*)(ws + 134217728);           // 12582912
    float*    bias  = (float*)   (ws + 146800640);           // 16384
    _Float16* hb0   = (_Float16*)(ws + 146817024);           // 524288 (swizzled hA)
    _Float16* hb1   = (_Float16*)(ws + 147341312);           // 524288
    float*    c_st  = (float*)   (ws + 147865600);           // 1048576
    float*    hf32  = (float*)   (ws + 148914176);           // 1048576
    float*    logit = (float*)   (ws + 149962752);           // 1048576

    k_transpose_x<<<dim3(16, 16, 256), dim3(32, 8), 0, stream>>>(x, xT);
    k_build_wswz<<<dim3(24, 64), 256, 0, stream>>>(
        Wgh, Wfh, Wih, Woh, Wgx, Wfx, Wix, Wox, Wswz);
    k_init<<<1024, 256, 0, stream>>>(c_st, (unsigned int*)hb0, bias, bg, bf, bi, bo);

    for (int t = 0; t < T_LEN; ++t) {
        const _Float16* hin = (t & 1) ? hb1 : hb0;
        _Float16*       hout = (t & 1) ? hb0 : hb1;
        k_step<<<256, 256, 0, stream>>>(hin, hout, hf32, c_st,
                                        xT + (size_t)t * B_SZ * D_IN, Wswz, bias,
                                        (t == T_LEN - 1) ? 1 : 0);
    }

    k_logits<<<dim3(16, 8), 256, 0, stream>>>(hf32, Wph, bp, logit);
    k_softmax<<<256, 256, 0, stream>>>(logit, outp);
}